// Round 1
// baseline (111.254 us; speedup 1.0000x reference)
//
#include <hip/hip_runtime.h>

#define NQ 12
#define NL 4
#define NS 4096          // 2^12 amplitudes
#define NTHREADS 256

__global__ __launch_bounds__(NTHREADS, 1) void qsim_kernel(
    const float* __restrict__ xin,   // (B,12)
    const float* __restrict__ wts,   // (4,12,3)
    const float* __restrict__ hw,    // (12,)
    const float* __restrict__ hb,    // (1,)
    float* __restrict__ out)         // (B,)
{
    __shared__ float2 stA[NS];           // 32 KB
    __shared__ float2 stB[NS];           // 32 KB (ping-pong for CNOT-ring permutation)
    __shared__ float  gm[NL * NQ][8];    // Rot gate matrices (u00,u01,u10,u11 as r,i)
    __shared__ int    pm[NL][NQ];        // per-layer GF(2) masks: L(e_j)
    __shared__ float  wred[NTHREADS / 64];

    const int b   = blockIdx.x;
    const int tid = threadIdx.x;

    // ---- one-time precompute (threads 0..47): Rot matrices + CNOT-ring masks ----
    if (tid < NL * NQ) {
        const int l = tid / NQ;
        const int j = tid - l * NQ;      // doubles as wire index (gm) and bit position (pm)
        const float phi = wts[tid * 3 + 0];
        const float th  = wts[tid * 3 + 1];
        const float om  = wts[tid * 3 + 2];
        const float ct  = cosf(0.5f * th), st = sinf(0.5f * th);
        const float apo = -0.5f * (phi + om), amo = -0.5f * (phi - om);
        const float epr = cosf(apo), epi = sinf(apo);
        const float emr = cosf(amo), emi = sinf(amo);
        float* g = gm[tid];
        g[0] =  epr * ct; g[1] =  epi * ct;   // u00 = ep*ct
        g[2] = -emr * st; g[3] =  emi * st;   // u01 = -conj(em)*st
        g[4] =  emr * st; g[5] =  emi * st;   // u10 = em*st
        g[6] =  epr * ct; g[7] = -epi * ct;   // u11 = conj(ep)*ct

        // CNOT ring for layer l has range r = l+1 (since (l % 11) + 1, l<4).
        // final[y] = s0[g_0(g_1(...g_11(y)))]  -> evaluate chain q=11..0 on e_j.
        const int r = l + 1;
        int x = 1 << j;
        for (int q = NQ - 1; q >= 0; --q) {
            const int cb = NQ - 1 - q;               // control bit position
            const int tw = (q + r) % NQ;             // target wire
            const int tb = NQ - 1 - tw;              // target bit position
            x ^= ((x >> cb) & 1) << tb;
        }
        pm[l][j] = x;
    }

    // ---- fused |0..0> + AngleEmbedding: product state ----
    // amp(i) = (prod_q mag_q(i)) * (-i)^popcount(i)
    float cv[NQ], sv[NQ];
    #pragma unroll
    for (int bp = 0; bp < NQ; ++bp) {
        const float a = 0.5f * xin[b * NQ + (NQ - 1 - bp)];   // qubit q = 11-bp
        cv[bp] = cosf(a);
        sv[bp] = sinf(a);
    }
    for (int i = tid; i < NS; i += NTHREADS) {
        float m = 1.f;
        #pragma unroll
        for (int bp = 0; bp < NQ; ++bp)
            m *= ((i >> bp) & 1) ? sv[bp] : cv[bp];
        const int k = __popc(i) & 3;
        float2 v;
        v.x = (k == 0) ? m : ((k == 2) ? -m : 0.f);
        v.y = (k == 1) ? -m : ((k == 3) ? m : 0.f);
        stA[i] = v;
    }
    __syncthreads();

    float2* src = stA;
    float2* dst = stB;

    for (int l = 0; l < NL; ++l) {
        // 12 Rot gates, in place
        for (int q = 0; q < NQ; ++q) {
            const int bp = NQ - 1 - q;
            const float* g = gm[l * NQ + q];
            const float u00r = g[0], u00i = g[1], u01r = g[2], u01i = g[3];
            const float u10r = g[4], u10i = g[5], u11r = g[6], u11i = g[7];
            for (int p = tid; p < NS / 2; p += NTHREADS) {
                const int i0 = ((p >> bp) << (bp + 1)) | (p & ((1 << bp) - 1));
                const int i1 = i0 | (1 << bp);
                const float2 a0 = src[i0];
                const float2 a1 = src[i1];
                float2 n0, n1;
                n0.x = u00r * a0.x - u00i * a0.y + u01r * a1.x - u01i * a1.y;
                n0.y = u00r * a0.y + u00i * a0.x + u01r * a1.y + u01i * a1.x;
                n1.x = u10r * a0.x - u10i * a0.y + u11r * a1.x - u11i * a1.y;
                n1.y = u10r * a0.y + u10i * a0.x + u11r * a1.y + u11i * a1.x;
                src[i0] = n0;
                src[i1] = n1;
            }
            __syncthreads();
        }
        // fused 12-CNOT ring: dst[y] = src[L(y)], L(y) = XOR of masks over set bits
        for (int y = tid; y < NS; y += NTHREADS) {
            int x = 0;
            #pragma unroll
            for (int j = 0; j < NQ; ++j)
                if ((y >> j) & 1) x ^= pm[l][j];
            dst[y] = src[x];
        }
        __syncthreads();
        float2* t = src; src = dst; dst = t;
    }

    // ---- fused <Z_q> + linear head: out[b] = sum_i |amp_i|^2 * coef(i) + hb ----
    float acc = 0.f;
    for (int i = tid; i < NS; i += NTHREADS) {
        const float2 a = src[i];
        const float pr = a.x * a.x + a.y * a.y;
        float coef = 0.f;
        #pragma unroll
        for (int q = 0; q < NQ; ++q)
            coef += ((i >> (NQ - 1 - q)) & 1) ? -hw[q] : hw[q];
        acc += pr * coef;
    }
    #pragma unroll
    for (int off = 32; off >= 1; off >>= 1)
        acc += __shfl_xor(acc, off, 64);
    if ((tid & 63) == 0) wred[tid >> 6] = acc;
    __syncthreads();
    if (tid == 0)
        out[b] = wred[0] + wred[1] + wred[2] + wred[3] + hb[0];
}

extern "C" void kernel_launch(void* const* d_in, const int* in_sizes, int n_in,
                              void* d_out, int out_size, void* d_ws, size_t ws_size,
                              hipStream_t stream) {
    const float* x  = (const float*)d_in[0];
    const float* w  = (const float*)d_in[1];
    const float* hw = (const float*)d_in[2];
    const float* hb = (const float*)d_in[3];
    float* outp = (float*)d_out;
    const int B = in_sizes[0] / NQ;      // 512
    qsim_kernel<<<B, NTHREADS, 0, stream>>>(x, w, hw, hb, outp);
}

// Round 2
// 52.275 us; speedup vs baseline: 2.1282x; 2.1282x over previous
//
#include <hip/hip_runtime.h>

#define NQ 12
#define NL 4
#define NS 4096          // 2^12 amplitudes
#define NT 512           // threads per block
#define KG 3             // gates fused per pass
#define TS 8             // tile size = 1<<KG
#define PPL 4            // passes per layer = NQ/KG
#define NPASS (NL*PPL)
#define NFREE (NQ-KG)    // free bits enumerating cosets

struct PassTab {
    unsigned sms[TS];    // sidx(xor of pairing-mask subset), indexed by local logical idx
    unsigned m[KG];      // pairing masks  m_i = M(e_qi)
    unsigned rq[KG];     // parity rows    r_i = row qi of M^-1
    unsigned gq[KG];     // gate matrix index l*NQ+q
    unsigned np[NFREE];  // nonpivot bit positions for coset enumeration
};
struct Tabs {
    PassTab p[NPASS];
    unsigned rfin[NQ];   // final parity rows (logical bit q of M_NL^-1 x)
};

__host__ __device__ constexpr unsigned sidx_c(unsigned x) {
    return x ^ ((x >> 4) & 15u) ^ ((x >> 8) & 15u);   // GF2-linear bank swizzle
}

constexpr unsigned gmap(int l, unsigned v) {
    // layer-l (0-based) CNOT-ring composed map: final[y] = s0[gmap(l, y)]
    int r = l + 1;
    unsigned x = v;
    for (int q = NQ - 1; q >= 0; --q) {
        int cb = NQ - 1 - q, tw = (q + r) % NQ, tb = NQ - 1 - tw;
        x ^= ((x >> cb) & 1u) << tb;
    }
    return x;
}

constexpr Tabs make_tabs() {
    Tabs T{};
    // cumulative maps: M_0 = I; M_l = M_{l-1} ∘ g_l  (columns as masks)
    unsigned Mcol[NL + 1][NQ]{};
    for (int bp = 0; bp < NQ; ++bp) Mcol[0][bp] = 1u << bp;
    for (int l = 1; l <= NL; ++l)
        for (int bp = 0; bp < NQ; ++bp) {
            unsigned gv = gmap(l - 1, 1u << bp), acc = 0;
            for (int j = 0; j < NQ; ++j) if ((gv >> j) & 1u) acc ^= Mcol[l - 1][j];
            Mcol[l][bp] = acc;
        }
    // inverse row masks: bit bp of M^-1(x) = parity(x & rmask[bp])
    unsigned rmask[NL + 1][NQ]{};
    for (int l = 0; l <= NL; ++l) {
        unsigned A[NQ]{}, Inv[NQ]{};
        for (int i = 0; i < NQ; ++i) {
            unsigned row = 0;
            for (int j = 0; j < NQ; ++j) row |= ((Mcol[l][j] >> i) & 1u) << j;
            A[i] = row; Inv[i] = 1u << i;
        }
        for (int c = 0; c < NQ; ++c) {
            int piv = c;
            while (!((A[piv] >> c) & 1u)) ++piv;
            unsigned ta = A[c]; A[c] = A[piv]; A[piv] = ta;
            unsigned ti = Inv[c]; Inv[c] = Inv[piv]; Inv[piv] = ti;
            for (int i = 0; i < NQ; ++i)
                if (i != c && ((A[i] >> c) & 1u)) { A[i] ^= A[c]; Inv[i] ^= Inv[c]; }
        }
        for (int i = 0; i < NQ; ++i) rmask[l][i] = Inv[i];
    }
    // per-pass tables: layer l (0-based), gates q = k*KG..k*KG+KG-1 use M_l
    for (int l = 0; l < NL; ++l)
        for (int k = 0; k < PPL; ++k) {
            PassTab& P = T.p[l * PPL + k];
            for (int g = 0; g < KG; ++g) {
                int q = k * KG + g;
                P.gq[g] = (unsigned)(l * NQ + q);
                P.m[g]  = Mcol[l][NQ - 1 - q];
                P.rq[g] = rmask[l][NQ - 1 - q];
            }
            for (int s = 0; s < TS; ++s) {
                unsigned x = 0;
                for (int g = 0; g < KG; ++g) if ((s >> g) & 1) x ^= P.m[g];
                P.sms[s] = sidx_c(x);
            }
            // echelon pivots of {m}: nonpivot positions enumerate cosets
            bool ispiv[NQ]{};
            unsigned red[KG]{};
            for (int g = 0; g < KG; ++g) {
                unsigned v = P.m[g];
                for (int h = 0; h < g; ++h) {
                    int pb = 31; while (!((red[h] >> pb) & 1u)) --pb;
                    if ((v >> pb) & 1u) v ^= red[h];
                }
                red[g] = v;
                int pb = 31; while (!((v >> pb) & 1u)) --pb;
                ispiv[pb] = true;
            }
            int c = 0;
            for (int bpos = 0; bpos < NQ; ++bpos)
                if (!ispiv[bpos]) P.np[c++] = (unsigned)bpos;
        }
    for (int q = 0; q < NQ; ++q) T.rfin[q] = rmask[NL][NQ - 1 - q];
    return T;
}

__constant__ Tabs TABS = make_tabs();

__global__ __launch_bounds__(NT, 4) void qsim_kernel(
    const float* __restrict__ xin,   // (B,12)
    const float* __restrict__ wts,   // (4,12,3)
    const float* __restrict__ hw,    // (12,)
    const float* __restrict__ hb,    // (1,)
    float* __restrict__ out)         // (B,)
{
    __shared__ float2 st[NS];            // 32 KB, swizzled storage
    __shared__ float  gm[NL * NQ][8];    // Rot matrices
    __shared__ float  wred[NT / 64];

    const int b   = blockIdx.x;
    const int tid = threadIdx.x;

    // ---- Rot gate matrices (threads 0..47) ----
    if (tid < NL * NQ) {
        const float phi = wts[tid * 3 + 0];
        const float th  = wts[tid * 3 + 1];
        const float om  = wts[tid * 3 + 2];
        const float ct  = cosf(0.5f * th), stt = sinf(0.5f * th);
        const float apo = -0.5f * (phi + om), amo = -0.5f * (phi - om);
        const float epr = cosf(apo), epi = sinf(apo);
        const float emr = cosf(amo), emi = sinf(amo);
        float* g = gm[tid];
        g[0] =  epr * ct; g[1] =  epi * ct;   // u00 = ep*ct
        g[2] = -emr * stt; g[3] =  emi * stt; // u01 = -conj(em)*st
        g[4] =  emr * stt; g[5] =  emi * stt; // u10 = em*st
        g[6] =  epr * ct; g[7] = -epi * ct;   // u11 = conj(ep)*ct
    }

    // ---- fused |0..0> + AngleEmbedding product state ----
    float cv[NQ], sv[NQ];
    #pragma unroll
    for (int bp = 0; bp < NQ; ++bp) {
        const float a = 0.5f * xin[b * NQ + (NQ - 1 - bp)];
        cv[bp] = cosf(a); sv[bp] = sinf(a);
    }
    #pragma unroll
    for (int k = 0; k < NS / NT; ++k) {
        const int i = tid + NT * k;
        float mg = 1.f;
        #pragma unroll
        for (int bp = 0; bp < NQ; ++bp)
            mg *= ((i >> bp) & 1) ? sv[bp] : cv[bp];
        const int pc = __popc(i) & 3;
        float2 v;
        v.x = (pc == 0) ? mg : ((pc == 2) ? -mg : 0.f);
        v.y = (pc == 1) ? -mg : ((pc == 3) ? mg : 0.f);
        st[sidx_c((unsigned)i)] = v;
    }
    __syncthreads();

    // ---- 16 passes of 3 register-fused gates; CNOT rings folded into masks ----
    for (int pass = 0; pass < NPASS; ++pass) {
        const PassTab& P = TABS.p[pass];
        // coset representative from the 9 free bits of tid
        unsigned x0 = 0;
        #pragma unroll
        for (int kk = 0; kk < NFREE; ++kk)
            x0 |= ((unsigned)((tid >> kk) & 1)) << P.np[kk];
        // shift rep so all KG local logical bits are zero
        #pragma unroll
        for (int g = 0; g < KG; ++g)
            if (__popc(x0 & P.rq[g]) & 1) x0 ^= P.m[g];
        const unsigned s0 = sidx_c(x0);

        float2 r[TS];
        #pragma unroll
        for (int s = 0; s < TS; ++s) r[s] = st[s0 ^ P.sms[s]];

        #pragma unroll
        for (int g = 0; g < KG; ++g) {
            const float* G = gm[P.gq[g]];
            const float u00r = G[0], u00i = G[1], u01r = G[2], u01i = G[3];
            const float u10r = G[4], u10i = G[5], u11r = G[6], u11i = G[7];
            #pragma unroll
            for (int h = 0; h < TS / 2; ++h) {
                const int l0 = ((h >> g) << (g + 1)) | (h & ((1 << g) - 1));
                const int l1 = l0 | (1 << g);
                const float2 a0 = r[l0], a1 = r[l1];
                r[l0].x = u00r * a0.x - u00i * a0.y + u01r * a1.x - u01i * a1.y;
                r[l0].y = u00r * a0.y + u00i * a0.x + u01r * a1.y + u01i * a1.x;
                r[l1].x = u10r * a0.x - u10i * a0.y + u11r * a1.x - u11i * a1.y;
                r[l1].y = u10r * a0.y + u10i * a0.x + u11r * a1.y + u11i * a1.x;
            }
        }

        #pragma unroll
        for (int s = 0; s < TS; ++s) st[s0 ^ P.sms[s]] = r[s];
        __syncthreads();
    }

    // ---- fused <Z_q> + linear head ----
    float acc = 0.f;
    #pragma unroll
    for (int k = 0; k < NS / NT; ++k) {
        const int i = tid + NT * k;
        const float2 a = st[sidx_c((unsigned)i)];
        const float pr = a.x * a.x + a.y * a.y;
        float coef = 0.f;
        #pragma unroll
        for (int q = 0; q < NQ; ++q)
            coef += (__popc((unsigned)i & TABS.rfin[q]) & 1) ? -hw[q] : hw[q];
        acc += pr * coef;
    }
    #pragma unroll
    for (int off = 32; off >= 1; off >>= 1)
        acc += __shfl_xor(acc, off, 64);
    if ((tid & 63) == 0) wred[tid >> 6] = acc;
    __syncthreads();
    if (tid == 0) {
        float s = 0.f;
        #pragma unroll
        for (int w = 0; w < NT / 64; ++w) s += wred[w];
        out[b] = s + hb[0];
    }
}

extern "C" void kernel_launch(void* const* d_in, const int* in_sizes, int n_in,
                              void* d_out, int out_size, void* d_ws, size_t ws_size,
                              hipStream_t stream) {
    const float* x  = (const float*)d_in[0];
    const float* w  = (const float*)d_in[1];
    const float* hw = (const float*)d_in[2];
    const float* hb = (const float*)d_in[3];
    float* outp = (float*)d_out;
    const int B = in_sizes[0] / NQ;      // 512
    qsim_kernel<<<B, NT, 0, stream>>>(x, w, hw, hb, outp);
}

// Round 3
// 50.882 us; speedup vs baseline: 2.1865x; 1.0274x over previous
//
#include <hip/hip_runtime.h>

#define NQ 12
#define NL 4
#define NS 4096          // 2^12 amplitudes
#define NT 128           // threads per block
#define KG 4             // gates fused per pass
#define TS 16            // tile size = 1<<KG (per coset; each lane holds 2 cosets)
#define PPL 3            // passes per layer
#define NPASS (NL*PPL)   // 12
#define NFREE 7          // 12 - KG - 1(pair bit)

typedef float f32x2 __attribute__((ext_vector_type(2)));

struct PassTab {
    unsigned xms[TS];    // physical subset XOR masks (span of m[])
    unsigned sms[TS];    // sidx(xms)
    unsigned m[KG];      // pairing masks  m_g = M(e_qg)
    unsigned rq[KG];     // parity rows    r_g = row qg of M^-1
    unsigned gq[KG];     // gate matrix index l*NQ+q
    unsigned np[NFREE];  // nonpivot bit positions for coset enumeration
    unsigned f, sf, rf;  // coset-pair mask, sidx(f), its parity row
};
struct Tabs {
    PassTab p[NPASS];
    unsigned rfin[NQ];   // final parity rows
    unsigned tmask[NQ];  // bit t: parity(xms_last[t] & rfin[q])
    unsigned fpar;       // bit q: parity(f_last & rfin[q])
};

constexpr unsigned sidx_c(unsigned x) { return x ^ ((x >> 4) & 15u) ^ ((x >> 8) & 15u); }

constexpr int pcnt(unsigned x) { int c = 0; while (x) { c += (int)(x & 1u); x >>= 1; } return c; }

constexpr unsigned gmap(int l, unsigned v) {
    int r = l + 1;
    unsigned x = v;
    for (int q = NQ - 1; q >= 0; --q) {
        int cb = NQ - 1 - q, tw = (q + r) % NQ, tb = NQ - 1 - tw;
        x ^= ((x >> cb) & 1u) << tb;
    }
    return x;
}

constexpr Tabs make_tabs() {
    Tabs T{};
    unsigned Mcol[NL + 1][NQ]{};
    for (int bp = 0; bp < NQ; ++bp) Mcol[0][bp] = 1u << bp;
    for (int l = 1; l <= NL; ++l)
        for (int bp = 0; bp < NQ; ++bp) {
            unsigned gv = gmap(l - 1, 1u << bp), acc = 0;
            for (int j = 0; j < NQ; ++j) if ((gv >> j) & 1u) acc ^= Mcol[l - 1][j];
            Mcol[l][bp] = acc;
        }
    unsigned rmask[NL + 1][NQ]{};
    for (int l = 0; l <= NL; ++l) {
        unsigned A[NQ]{}, Inv[NQ]{};
        for (int i = 0; i < NQ; ++i) {
            unsigned row = 0;
            for (int j = 0; j < NQ; ++j) row |= ((Mcol[l][j] >> i) & 1u) << j;
            A[i] = row; Inv[i] = 1u << i;
        }
        for (int c = 0; c < NQ; ++c) {
            int piv = c;
            while (!((A[piv] >> c) & 1u)) ++piv;
            unsigned ta = A[c]; A[c] = A[piv]; A[piv] = ta;
            unsigned ti = Inv[c]; Inv[c] = Inv[piv]; Inv[piv] = ti;
            for (int i = 0; i < NQ; ++i)
                if (i != c && ((A[i] >> c) & 1u)) { A[i] ^= A[c]; Inv[i] ^= Inv[c]; }
        }
        for (int i = 0; i < NQ; ++i) rmask[l][i] = Inv[i];
    }
    for (int l = 0; l < NL; ++l)
        for (int k = 0; k < PPL; ++k) {
            PassTab& P = T.p[l * PPL + k];
            for (int g = 0; g < KG; ++g) {
                int q = k * KG + g;
                P.gq[g] = (unsigned)(l * NQ + q);
                P.m[g]  = Mcol[l][NQ - 1 - q];
                P.rq[g] = rmask[l][NQ - 1 - q];
            }
            int qp = (k * KG + KG) % NQ;        // a wire in another group
            P.f  = Mcol[l][NQ - 1 - qp];
            P.rf = rmask[l][NQ - 1 - qp];
            P.sf = sidx_c(P.f);
            for (int s = 0; s < TS; ++s) {
                unsigned x = 0;
                for (int g = 0; g < KG; ++g) if ((s >> g) & 1) x ^= P.m[g];
                P.xms[s] = x; P.sms[s] = sidx_c(x);
            }
            // echelon over {m[0..3], f} -> nonpivot bits enumerate cosets
            unsigned arr[KG + 1]{};
            for (int g = 0; g < KG; ++g) arr[g] = P.m[g];
            arr[KG] = P.f;
            bool ispiv[NQ]{};
            unsigned red[KG + 1]{};
            for (int g = 0; g < KG + 1; ++g) {
                unsigned v = arr[g];
                for (int h = 0; h < g; ++h) {
                    int pb = 31; while (!((red[h] >> pb) & 1u)) --pb;
                    if ((v >> pb) & 1u) v ^= red[h];
                }
                red[g] = v;
                int pb = 31; while (!((v >> pb) & 1u)) --pb;
                ispiv[pb] = true;
            }
            int c = 0;
            for (int bpos = 0; bpos < NQ; ++bpos)
                if (!ispiv[bpos]) P.np[c++] = (unsigned)bpos;
        }
    for (int q = 0; q < NQ; ++q) T.rfin[q] = rmask[NL][NQ - 1 - q];
    for (int q = 0; q < NQ; ++q) {
        unsigned tm = 0;
        for (int t = 0; t < TS; ++t)
            tm |= (unsigned)(pcnt(T.p[NPASS - 1].xms[t] & T.rfin[q]) & 1) << t;
        T.tmask[q] = tm;
        T.fpar |= (unsigned)(pcnt(T.p[NPASS - 1].f & T.rfin[q]) & 1) << q;
    }
    return T;
}

__constant__ Tabs TABS = make_tabs();
constexpr Tabs CT = make_tabs();     // compile-time copy for peeled first/last passes

__device__ __forceinline__ unsigned sidx(unsigned x) { return x ^ ((x >> 4) & 15u) ^ ((x >> 8) & 15u); }
__device__ __forceinline__ int par(unsigned x) { return __popc(x) & 1; }

__device__ __forceinline__ unsigned coset_rep(int tid, const PassTab& P) {
    unsigned x0 = 0;
    #pragma unroll
    for (int k = 0; k < NFREE; ++k)
        x0 |= ((unsigned)((tid >> k) & 1)) << P.np[k];
    #pragma unroll
    for (int g = 0; g < KG; ++g)
        if (par(x0 & P.rq[g])) x0 ^= P.m[g];
    if (par(x0 & P.rf)) x0 ^= P.f;
    return x0;
}

__device__ __forceinline__ void apply4(f32x2 rp[TS], f32x2 ip[TS],
                                       const float (*gm)[8], const unsigned* gq) {
    #pragma unroll
    for (int g = 0; g < KG; ++g) {
        const float* G = gm[gq[g]];
        const float c00r = G[0], c00i = G[1], c01r = G[2], c01i = G[3];
        const float c10r = G[4], c10i = G[5], c11r = G[6], c11i = G[7];
        #pragma unroll
        for (int h = 0; h < TS / 2; ++h) {
            const int t0 = ((h >> g) << (g + 1)) | (h & ((1 << g) - 1));
            const int t1 = t0 | (1 << g);
            const f32x2 a0r = rp[t0], a0i = ip[t0], a1r = rp[t1], a1i = ip[t1];
            rp[t0] = a0r * c00r - a0i * c00i + a1r * c01r - a1i * c01i;
            ip[t0] = a0i * c00r + a0r * c00i + a1i * c01r + a1r * c01i;
            rp[t1] = a0r * c10r - a0i * c10i + a1r * c11r - a1i * c11i;
            ip[t1] = a0i * c10r + a0r * c10i + a1i * c11r + a1r * c11i;
        }
    }
}

__global__ __launch_bounds__(NT) void qsim_kernel(
    const float* __restrict__ xin,   // (B,12)
    const float* __restrict__ wts,   // (4,12,3)
    const float* __restrict__ hw,    // (12,)
    const float* __restrict__ hb,    // (1,)
    float* __restrict__ out)         // (B,)
{
    __shared__ float2 st[NS];            // 32 KB
    __shared__ float  gm[NL * NQ][8];
    __shared__ float  wred[2];

    const int b   = blockIdx.x;
    const int tid = threadIdx.x;

    if (tid < NL * NQ) {
        const float phi = wts[tid * 3 + 0];
        const float th  = wts[tid * 3 + 1];
        const float om  = wts[tid * 3 + 2];
        const float ct  = cosf(0.5f * th), stt = sinf(0.5f * th);
        const float apo = -0.5f * (phi + om), amo = -0.5f * (phi - om);
        const float epr = cosf(apo), epi = sinf(apo);
        const float emr = cosf(amo), emi = sinf(amo);
        float* g = gm[tid];
        g[0] =  epr * ct;  g[1] =  epi * ct;
        g[2] = -emr * stt; g[3] =  emi * stt;
        g[4] =  emr * stt; g[5] =  emi * stt;
        g[6] =  epr * ct;  g[7] = -epi * ct;
    }

    float cv[NQ], sv[NQ];
    #pragma unroll
    for (int bp = 0; bp < NQ; ++bp) {
        const float a = 0.5f * xin[b * NQ + (NQ - 1 - bp)];
        cv[bp] = cosf(a); sv[bp] = sinf(a);
    }

    f32x2 rp[TS], ip[TS];

    // ---- pass 0 (peeled): product-state init directly in registers ----
    {
        constexpr PassTab P = CT.p[0];
        const unsigned x0 = coset_rep(tid, P);
        #pragma unroll
        for (int t = 0; t < TS; ++t) {
            const unsigned iA = x0 ^ P.xms[t];
            const unsigned iB = iA ^ P.f;
            float mA = 1.f, mB = 1.f;
            #pragma unroll
            for (int bp = 0; bp < NQ; ++bp) {
                mA *= ((iA >> bp) & 1) ? sv[bp] : cv[bp];
                mB *= ((iB >> bp) & 1) ? sv[bp] : cv[bp];
            }
            const int pA = __popc(iA) & 3, pB = __popc(iB) & 3;
            const float rA  = (pA == 0) ? mA : ((pA == 2) ? -mA : 0.f);
            const float iAv = (pA == 1) ? -mA : ((pA == 3) ? mA : 0.f);
            const float rB  = (pB == 0) ? mB : ((pB == 2) ? -mB : 0.f);
            const float iBv = (pB == 1) ? -mB : ((pB == 3) ? mB : 0.f);
            rp[t] = f32x2{rA, rB};
            ip[t] = f32x2{iAv, iBv};
        }
        __syncthreads();                      // gm ready
        apply4(rp, ip, gm, P.gq);
        const unsigned sA = sidx(x0);
        #pragma unroll
        for (int t = 0; t < TS; ++t) {
            st[sA ^ P.sms[t]]        = make_float2(rp[t].x, ip[t].x);
            st[sA ^ P.sms[t] ^ P.sf] = make_float2(rp[t].y, ip[t].y);
        }
    }
    __syncthreads();

    // ---- middle passes 1..10 ----
    for (int pass = 1; pass < NPASS - 1; ++pass) {
        const PassTab& P = TABS.p[pass];
        const unsigned x0 = coset_rep(tid, P);
        const unsigned sA = sidx(x0);
        #pragma unroll
        for (int t = 0; t < TS; ++t) {
            const float2 a  = st[sA ^ P.sms[t]];
            const float2 bm = st[sA ^ P.sms[t] ^ P.sf];
            rp[t] = f32x2{a.x, bm.x};
            ip[t] = f32x2{a.y, bm.y};
        }
        apply4(rp, ip, gm, P.gq);
        #pragma unroll
        for (int t = 0; t < TS; ++t) {
            st[sA ^ P.sms[t]]        = make_float2(rp[t].x, ip[t].x);
            st[sA ^ P.sms[t] ^ P.sf] = make_float2(rp[t].y, ip[t].y);
        }
        __syncthreads();
    }

    // ---- pass 11 (peeled): gates then fused <Z>+head reduction from registers ----
    {
        constexpr PassTab P = CT.p[NPASS - 1];
        const unsigned x0 = coset_rep(tid, P);
        const unsigned sA = sidx(x0);
        #pragma unroll
        for (int t = 0; t < TS; ++t) {
            const float2 a  = st[sA ^ P.sms[t]];
            const float2 bm = st[sA ^ P.sms[t] ^ P.sf];
            rp[t] = f32x2{a.x, bm.x};
            ip[t] = f32x2{a.y, bm.y};
        }
        apply4(rp, ip, gm, P.gq);

        f32x2 pr[TS];
        #pragma unroll
        for (int t = 0; t < TS; ++t)
            pr[t] = rp[t] * rp[t] + ip[t] * ip[t];

        f32x2 acc = f32x2{0.f, 0.f};
        #pragma unroll
        for (int q = 0; q < NQ; ++q) {
            f32x2 Tq = f32x2{0.f, 0.f};
            #pragma unroll
            for (int t = 0; t < TS; ++t) {
                if ((CT.tmask[q] >> t) & 1) Tq -= pr[t]; else Tq += pr[t];
            }
            const float wq = par(x0 & CT.rfin[q]) ? -hw[q] : hw[q];
            const f32x2 wv = f32x2{wq, ((CT.fpar >> q) & 1) ? -wq : wq};
            acc += wv * Tq;
        }
        float s = acc.x + acc.y;
        #pragma unroll
        for (int off = 32; off >= 1; off >>= 1)
            s += __shfl_xor(s, off, 64);
        if ((tid & 63) == 0) wred[tid >> 6] = s;
        __syncthreads();
        if (tid == 0) out[b] = wred[0] + wred[1] + hb[0];
    }
}

extern "C" void kernel_launch(void* const* d_in, const int* in_sizes, int n_in,
                              void* d_out, int out_size, void* d_ws, size_t ws_size,
                              hipStream_t stream) {
    const float* x  = (const float*)d_in[0];
    const float* w  = (const float*)d_in[1];
    const float* hw = (const float*)d_in[2];
    const float* hb = (const float*)d_in[3];
    float* outp = (float*)d_out;
    const int B = in_sizes[0] / NQ;      // 512
    qsim_kernel<<<B, NT, 0, stream>>>(x, w, hw, hb, outp);
}

// Round 4
// 45.760 us; speedup vs baseline: 2.4313x; 1.1119x over previous
//
#include <hip/hip_runtime.h>

#define NQ 12
#define NL 4
#define NT 128            // 2 waves; wave w owns state bit11 == w
// state: 4096 amps; per lane 32 amps (slot bits 0..4), lane bits 5..10, wave bit 11

typedef float f32x2 __attribute__((ext_vector_type(2)));

constexpr unsigned sidx_c(unsigned x) { return x ^ ((x >> 4) & 15u) ^ ((x >> 8) & 15u); }

constexpr unsigned gmap(int l, unsigned v) {
    // layer-l CNOT-ring composed map (verified round 1): new[y] = old[XOR_{j in y} gmap(l,1<<j)]
    int r = l + 1;
    unsigned x = v;
    for (int q = NQ - 1; q >= 0; --q) {
        int cb = NQ - 1 - q, tw = (q + r) % NQ, tb = NQ - 1 - tw;
        x ^= ((x >> cb) & 1u) << tb;
    }
    return x;
}

struct Tabs { unsigned pmB[NL][NQ]; };   // sidx(gmap(l,e_j)) << 3  (LDS byte offsets)
constexpr Tabs make_tabs() {
    Tabs T{};
    for (int l = 0; l < NL; ++l)
        for (int j = 0; j < NQ; ++j)
            T.pmB[l][j] = sidx_c(gmap(l, 1u << j)) << 3;
    return T;
}
__constant__ Tabs TB = make_tabs();

__device__ __forceinline__ unsigned dsidx(unsigned x) { return x ^ ((x >> 4) & 15u) ^ ((x >> 8) & 15u); }

__global__ __launch_bounds__(NT) void qsim_kernel(
    const float* __restrict__ xin,   // (B,12)
    const float* __restrict__ wts,   // (4,12,3)
    const float* __restrict__ hw,    // (12,)
    const float* __restrict__ hb,    // (1,)
    float* __restrict__ out)         // (B,)
{
    __shared__ float2 bufA[4096];        // 32 KB : w-gate exchange
    __shared__ float2 bufB[4096];        // 32 KB : ring gather
    __shared__ float  gm[NL * NQ][8];
    __shared__ float  wred[2];

    const int tid  = threadIdx.x;
    const int lane = tid & 63;
    const int w    = tid >> 6;
    const int b    = blockIdx.x;

    // ---- Rot gate matrices (threads 0..47) ----
    if (tid < NL * NQ) {
        const float phi = wts[tid * 3 + 0];
        const float th  = wts[tid * 3 + 1];
        const float om  = wts[tid * 3 + 2];
        const float ct  = cosf(0.5f * th), stt = sinf(0.5f * th);
        const float apo = -0.5f * (phi + om), amo = -0.5f * (phi - om);
        const float epr = cosf(apo), epi = sinf(apo);
        const float emr = cosf(amo), emi = sinf(amo);
        float* g = gm[tid];
        g[0] =  epr * ct;  g[1] =  epi * ct;   // u00
        g[2] = -emr * stt; g[3] =  emi * stt;  // u01
        g[4] =  emr * stt; g[5] =  emi * stt;  // u10
        g[6] =  epr * ct;  g[7] = -epi * ct;   // u11
    }

    // ---- angles (bit position bp <-> wire 11-bp) ----
    float cv[NQ], sv[NQ];
    #pragma unroll
    for (int bp = 0; bp < NQ; ++bp) {
        const float a = 0.5f * xin[b * NQ + (NQ - 1 - bp)];
        cv[bp] = cosf(a); sv[bp] = sinf(a);
    }

    // ---- init product state directly in registers ----
    // amp(x) = (prod_bp mag) * (-i)^popc(x);  x = (w<<11)|(lane<<5)|slot
    f32x2 rp[16], ip[16];
    {
        float MLW = w ? sv[11] : cv[11];
        #pragma unroll
        for (int bp = 5; bp <= 10; ++bp)
            MLW *= ((lane >> (bp - 5)) & 1) ? sv[bp] : cv[bp];
        const int pcLW = (__popc((unsigned)lane) + w) & 3;
        const float plr = (pcLW == 0) ? 1.f : ((pcLW == 2) ? -1.f : 0.f);
        const float pli = (pcLW == 1) ? -1.f : ((pcLW == 3) ? 1.f : 0.f);
        float MS[32];
        MS[0] = cv[0]; MS[1] = sv[0];
        #pragma unroll
        for (int bit = 1; bit < 5; ++bit) {
            #pragma unroll
            for (int j = (1 << bit) - 1; j >= 0; --j) {
                MS[j | (1 << bit)] = MS[j] * sv[bit];
                MS[j]              = MS[j] * cv[bit];
            }
        }
        #pragma unroll
        for (int s = 0; s < 32; ++s) {
            const float m = MLW * MS[s];
            const int pcS = __builtin_popcount((unsigned)s) & 3;
            float ar, ai;
            if      (pcS == 0) { ar =  m * plr; ai =  m * pli; }
            else if (pcS == 1) { ar =  m * pli; ai = -m * plr; }
            else if (pcS == 2) { ar = -m * plr; ai = -m * pli; }
            else               { ar = -m * pli; ai =  m * plr; }
            const int k = s >> 1;
            if (s & 1) { rp[k].y = ar; ip[k].y = ai; }
            else       { rp[k].x = ar; ip[k].x = ai; }
        }
    }
    __syncthreads();   // gm ready

    // LDS byte base for my 32 amps (state element x -> byte 8*sidx(x))
    const unsigned wbyte = dsidx(((unsigned)w << 11) | ((unsigned)lane << 5)) << 3;

    for (int l = 0; l < NL; ++l) {
        // ======== wire 0 (bit 11): cross-wave gate via LDS ========
        {
            const float* G = gm[l * NQ + 0];
            #pragma unroll
            for (int s = 0; s < 32; ++s) {
                const unsigned off = wbyte ^ (unsigned)(((s ^ (s >> 4)) << 3));
                const int k = s >> 1;
                *(float2*)((char*)bufA + off) =
                    make_float2((s & 1) ? rp[k].y : rp[k].x, (s & 1) ? ip[k].y : ip[k].x);
            }
            __syncthreads();
            const float cMer = w ? G[6] : G[0], cMei = w ? G[7] : G[1];
            const float cOtr = w ? G[4] : G[2], cOti = w ? G[5] : G[3];
            #pragma unroll
            for (int s = 0; s < 32; ++s) {
                const unsigned off = wbyte ^ (unsigned)(((s ^ (s >> 4)) << 3)) ^ 0x4040u; // ^ sidx(0x800)*8
                const float2 t = *(const float2*)((const char*)bufA + off);
                const int k = s >> 1;
                const float mr = (s & 1) ? rp[k].y : rp[k].x;
                const float mi = (s & 1) ? ip[k].y : ip[k].x;
                const float nr = cMer * mr - cMei * mi + cOtr * t.x - cOti * t.y;
                const float ni = cMei * mr + cMer * mi + cOti * t.x + cOtr * t.y;
                if (s & 1) { rp[k].y = nr; ip[k].y = ni; }
                else       { rp[k].x = nr; ip[k].x = ni; }
            }
        }

        // ======== wires 1..6 (bits 10..5 = lane bits 5..0): shfl_xor gates ========
        #pragma unroll
        for (int g = 1; g <= 6; ++g) {
            const float* G = gm[l * NQ + g];
            const int lb = (lane >> (6 - g)) & 1;
            const int m  = 1 << (6 - g);
            const float cMer = lb ? G[6] : G[0], cMei = lb ? G[7] : G[1];
            const float cOtr = lb ? G[4] : G[2], cOti = lb ? G[5] : G[3];
            #pragma unroll
            for (int k = 0; k < 16; ++k) {
                f32x2 tR, tI;
                tR.x = __shfl_xor(rp[k].x, m, 64); tR.y = __shfl_xor(rp[k].y, m, 64);
                tI.x = __shfl_xor(ip[k].x, m, 64); tI.y = __shfl_xor(ip[k].y, m, 64);
                const f32x2 nr = cMer * rp[k] - cMei * ip[k] + cOtr * tR - cOti * tI;
                const f32x2 ni = cMei * rp[k] + cMer * ip[k] + cOti * tR + cOtr * tI;
                rp[k] = nr; ip[k] = ni;
            }
        }

        // ======== wires 7..10 (bits 4..1 = reg bits 3..0): register gates ========
        #pragma unroll
        for (int wq = 7; wq <= 10; ++wq) {
            const float* G = gm[l * NQ + wq];
            const int rb = (11 - wq) - 1;       // 3..0
            const float u00r = G[0], u00i = G[1], u01r = G[2], u01i = G[3];
            const float u10r = G[4], u10i = G[5], u11r = G[6], u11i = G[7];
            #pragma unroll
            for (int h = 0; h < 8; ++h) {
                const int k0 = ((h >> rb) << (rb + 1)) | (h & ((1 << rb) - 1));
                const int k1 = k0 | (1 << rb);
                const f32x2 a0r = rp[k0], a0i = ip[k0], a1r = rp[k1], a1i = ip[k1];
                rp[k0] = u00r * a0r - u00i * a0i + u01r * a1r - u01i * a1i;
                ip[k0] = u00i * a0r + u00r * a0i + u01i * a1r + u01r * a1i;
                rp[k1] = u10r * a0r - u10i * a0i + u11r * a1r - u11i * a1i;
                ip[k1] = u10i * a0r + u10r * a0i + u11i * a1r + u11r * a1i;
            }
        }

        // ======== wire 11 (bit 0): intra-f32x2 gate ========
        {
            const float* G = gm[l * NQ + 11];
            const float u00r = G[0], u00i = G[1], u01r = G[2], u01i = G[3];
            const float u10r = G[4], u10i = G[5], u11r = G[6], u11i = G[7];
            #pragma unroll
            for (int k = 0; k < 16; ++k) {
                const float a0r = rp[k].x, a0i = ip[k].x, a1r = rp[k].y, a1i = ip[k].y;
                rp[k].x = u00r * a0r - u00i * a0i + u01r * a1r - u01i * a1i;
                ip[k].x = u00i * a0r + u00r * a0i + u01i * a1r + u01r * a1i;
                rp[k].y = u10r * a0r - u10i * a0i + u11r * a1r - u11i * a1i;
                ip[k].y = u10i * a0r + u10r * a0i + u11i * a1r + u11r * a1i;
            }
        }

        // ======== fused 12-CNOT ring: gather new[y]=old[XOR pm columns] ========
        #pragma unroll
        for (int s = 0; s < 32; ++s) {
            const unsigned off = wbyte ^ (unsigned)(((s ^ (s >> 4)) << 3));
            const int k = s >> 1;
            *(float2*)((char*)bufB + off) =
                make_float2((s & 1) ? rp[k].y : rp[k].x, (s & 1) ? ip[k].y : ip[k].x);
        }
        __syncthreads();
        unsigned gb = w ? TB.pmB[l][11] : 0u;
        #pragma unroll
        for (int j = 5; j <= 10; ++j)
            gb ^= ((lane >> (j - 5)) & 1) ? TB.pmB[l][j] : 0u;
        const unsigned p0 = TB.pmB[l][0], p1 = TB.pmB[l][1], p2 = TB.pmB[l][2],
                       p3 = TB.pmB[l][3], p4 = TB.pmB[l][4];
        #pragma unroll
        for (int k = 0; k < 16; ++k) {
            const int s0 = 2 * k, s1 = 2 * k + 1;
            unsigned a0 = gb, a1 = gb;
            if (s0 & 1)  a0 ^= p0;  if (s0 & 2)  a0 ^= p1;  if (s0 & 4)  a0 ^= p2;
            if (s0 & 8)  a0 ^= p3;  if (s0 & 16) a0 ^= p4;
            if (s1 & 1)  a1 ^= p0;  if (s1 & 2)  a1 ^= p1;  if (s1 & 4)  a1 ^= p2;
            if (s1 & 8)  a1 ^= p3;  if (s1 & 16) a1 ^= p4;
            const float2 v0 = *(const float2*)((const char*)bufB + a0);
            const float2 v1 = *(const float2*)((const char*)bufB + a1);
            rp[k] = f32x2{v0.x, v1.x};
            ip[k] = f32x2{v0.y, v1.y};
        }
        __syncthreads();
    }

    // ---- fused <Z_q> + linear head ----
    {
        float CS[32];                         // wires 7..11 (slot bits 4..0)
        CS[0] = hw[11]; CS[1] = -hw[11];
        #pragma unroll
        for (int bit = 1; bit < 5; ++bit) {
            const float h = hw[11 - bit];
            #pragma unroll
            for (int j = (1 << bit) - 1; j >= 0; --j) {
                CS[j | (1 << bit)] = CS[j] - h;
                CS[j]              = CS[j] + h;
            }
        }
        float CW = w ? -hw[0] : hw[0];        // wires 0..6 (w + lane bits)
        #pragma unroll
        for (int q = 1; q <= 6; ++q)
            CW += ((lane >> (6 - q)) & 1) ? -hw[q] : hw[q];

        f32x2 acc = f32x2{0.f, 0.f};
        #pragma unroll
        for (int k = 0; k < 16; ++k) {
            const f32x2 pr = rp[k] * rp[k] + ip[k] * ip[k];
            const f32x2 cc = f32x2{CW + CS[2 * k], CW + CS[2 * k + 1]};
            acc += pr * cc;
        }
        float sres = acc.x + acc.y;
        #pragma unroll
        for (int off = 32; off >= 1; off >>= 1)
            sres += __shfl_xor(sres, off, 64);
        if ((tid & 63) == 0) wred[w] = sres;
        __syncthreads();
        if (tid == 0) out[b] = wred[0] + wred[1] + hb[0];
    }
}

extern "C" void kernel_launch(void* const* d_in, const int* in_sizes, int n_in,
                              void* d_out, int out_size, void* d_ws, size_t ws_size,
                              hipStream_t stream) {
    const float* x  = (const float*)d_in[0];
    const float* wt = (const float*)d_in[1];
    const float* hw = (const float*)d_in[2];
    const float* hb = (const float*)d_in[3];
    float* outp = (float*)d_out;
    const int B = in_sizes[0] / NQ;      // 512
    qsim_kernel<<<B, NT, 0, stream>>>(x, wt, hw, hb, outp);
}

// Round 5
// 35.009 us; speedup vs baseline: 3.1779x; 1.3071x over previous
//
#include <hip/hip_runtime.h>

#define NQ 12
#define NL 4
#define NT 256
// state bits: 11,10 = wave id (4 waves), 9..4 = lane bits 5..0, 3..0 = slot
// per lane: 16 amps in 8 f32x2 pairs (slot bit0 = f32x2 component)

typedef float f32x2 __attribute__((ext_vector_type(2)));

constexpr unsigned sidx_c(unsigned x) { return x ^ ((x >> 4) & 15u) ^ ((x >> 8) & 15u); }

constexpr unsigned gmap_inv(int l, unsigned v) {
    // inverse of the layer-l fused CNOT-ring map (CNOTs self-inverse, reversed order)
    int r = l + 1; unsigned x = v;
    for (int q = 0; q < NQ; ++q) {
        int cb = NQ - 1 - q, tw = (q + r) % NQ, tb = NQ - 1 - tw;
        x ^= ((x >> cb) & 1u) << tb;
    }
    return x;
}

struct Tabs {
    unsigned lcol[NL][8];   // scatter byte-cols: [0..5]=state bits 4..9, [6]=bit10, [7]=bit11
    unsigned scol[NL][16];  // scatter byte-offset per slot nibble
};
constexpr Tabs make_tabs() {
    Tabs T{};
    for (int l = 0; l < NL; ++l) {
        unsigned colb[12];
        for (int bit = 0; bit < 12; ++bit) colb[bit] = sidx_c(gmap_inv(l, 1u << bit)) << 3;
        for (int j = 0; j < 6; ++j) T.lcol[l][j] = colb[4 + j];
        T.lcol[l][6] = colb[10];
        T.lcol[l][7] = colb[11];
        for (int s = 0; s < 16; ++s) {
            unsigned v = 0;
            for (int bp = 0; bp < 4; ++bp) if ((s >> bp) & 1) v ^= colb[bp];
            T.scol[l][s] = v;
        }
    }
    return T;
}
__constant__ Tabs TB = make_tabs();

__device__ __forceinline__ unsigned dsidx(unsigned x) { return x ^ ((x >> 4) & 15u) ^ ((x >> 8) & 15u); }

template<int IMM>
__device__ __forceinline__ f32x2 swz2(f32x2 v) {
    f32x2 r;
    r.x = __int_as_float(__builtin_amdgcn_ds_swizzle(__float_as_int(v.x), IMM));
    r.y = __int_as_float(__builtin_amdgcn_ds_swizzle(__float_as_int(v.y), IMM));
    return r;
}
template<int CTRL>
__device__ __forceinline__ f32x2 dpp2(f32x2 v) {
    f32x2 r;
    r.x = __int_as_float(__builtin_amdgcn_update_dpp(__float_as_int(v.x), __float_as_int(v.x), CTRL, 0xF, 0xF, false));
    r.y = __int_as_float(__builtin_amdgcn_update_dpp(__float_as_int(v.y), __float_as_int(v.y), CTRL, 0xF, 0xF, false));
    return r;
}
__device__ __forceinline__ f32x2 shfl2(f32x2 v, int m) {
    f32x2 r; r.x = __shfl_xor(v.x, m, 64); r.y = __shfl_xor(v.y, m, 64); return r;
}

__global__ __launch_bounds__(NT) void qsim_kernel(
    const float* __restrict__ xin,   // (B,12)
    const float* __restrict__ wts,   // (4,12,3)
    const float* __restrict__ hw,    // (12,)
    const float* __restrict__ hb,    // (1,)
    float* __restrict__ out)         // (B,)
{
    __shared__ float2 stbuf[2][4096];    // 64 KB double buffer
    __shared__ float  gm[NL * NQ][8];
    __shared__ float  wred[4];

    const int tid  = threadIdx.x;
    const int lane = tid & 63;
    const int wv   = tid >> 6;           // 2 wave bits = state bits 10 (wv&1), 11 (wv>>1)
    const int b    = blockIdx.x;

    // ---- Rot gate matrices (threads 0..47) ----
    if (tid < NL * NQ) {
        const float phi = wts[tid * 3 + 0];
        const float th  = wts[tid * 3 + 1];
        const float om  = wts[tid * 3 + 2];
        const float ct  = cosf(0.5f * th), stt = sinf(0.5f * th);
        const float apo = -0.5f * (phi + om), amo = -0.5f * (phi - om);
        const float epr = cosf(apo), epi = sinf(apo);
        const float emr = cosf(amo), emi = sinf(amo);
        float* g = gm[tid];
        g[0] =  epr * ct;  g[1] =  epi * ct;   // u00
        g[2] = -emr * stt; g[3] =  emi * stt;  // u01
        g[4] =  emr * stt; g[5] =  emi * stt;  // u10
        g[6] =  epr * ct;  g[7] = -epi * ct;   // u11
    }

    // ---- angles (bit bp <-> wire 11-bp) ----
    float cv[NQ], sv[NQ];
    #pragma unroll
    for (int bp = 0; bp < NQ; ++bp) {
        const float a = 0.5f * xin[b * NQ + (NQ - 1 - bp)];
        cv[bp] = cosf(a); sv[bp] = sinf(a);
    }

    const unsigned xbase = ((unsigned)wv << 10) | ((unsigned)lane << 4);
    const unsigned wbyte = dsidx(xbase) << 3;

    // ---- init product state, write to stbuf[0] ----
    {
        float MLW = 1.f;
        #pragma unroll
        for (int j = 0; j < 6; ++j) MLW *= ((lane >> j) & 1) ? sv[4 + j] : cv[4 + j];
        MLW *= (wv & 1) ? sv[10] : cv[10];
        MLW *= (wv >> 1) ? sv[11] : cv[11];
        const int pcLW = (__popc((unsigned)lane) + __popc((unsigned)wv)) & 3;
        const float plr = (pcLW == 0) ? 1.f : ((pcLW == 2) ? -1.f : 0.f);
        const float pli = (pcLW == 1) ? -1.f : ((pcLW == 3) ? 1.f : 0.f);
        float MS[16];
        MS[0] = cv[0]; MS[1] = sv[0];
        #pragma unroll
        for (int bit = 1; bit < 4; ++bit) {
            #pragma unroll
            for (int j = (1 << bit) - 1; j >= 0; --j) {
                MS[j | (1 << bit)] = MS[j] * sv[bit];
                MS[j]              = MS[j] * cv[bit];
            }
        }
        #pragma unroll
        for (int s = 0; s < 16; ++s) {
            const float m = MLW * MS[s];
            const int pcS = __builtin_popcount((unsigned)s) & 3;
            float ar, ai;
            if      (pcS == 0) { ar =  m * plr; ai =  m * pli; }
            else if (pcS == 1) { ar =  m * pli; ai = -m * plr; }
            else if (pcS == 2) { ar = -m * plr; ai = -m * pli; }
            else               { ar = -m * pli; ai =  m * plr; }
            *(float2*)((char*)stbuf[0] + (wbyte ^ ((unsigned)s << 3))) = make_float2(ar, ai);
        }
    }
    __syncthreads();   // init state + gm visible

    f32x2 rp[8], ip[8];
    const int b11 = wv >> 1, b10 = wv & 1;

    for (int l = 0; l < NL; ++l) {
        const float2* rb = stbuf[l & 1];
        float2*       wb = stbuf[(l + 1) & 1];

        // ==== fused read + wires 0,1 (wave-bit Rot pair, 4-term butterfly) ====
        {
            const float4 ga0 = *(const float4*)(&gm[l * NQ + 0][0]);
            const float4 gb0 = *(const float4*)(&gm[l * NQ + 0][4]);
            const float4 ga1 = *(const float4*)(&gm[l * NQ + 1][0]);
            const float4 gb1 = *(const float4*)(&gm[l * NQ + 1][4]);
            const float d0r = b11 ? gb0.z : ga0.x, d0i = b11 ? gb0.w : ga0.y;
            const float o0r = b11 ? gb0.x : ga0.z, o0i = b11 ? gb0.y : ga0.w;
            const float d1r = b10 ? gb1.z : ga1.x, d1i = b10 ? gb1.w : ga1.y;
            const float o1r = b10 ? gb1.x : ga1.z, o1i = b10 ? gb1.y : ga1.w;
            const float dwr  = d0r * d1r - d0i * d1i, dwi  = d0r * d1i + d0i * d1r; // own
            const float dp1r = o0r * d1r - o0i * d1i, dp1i = o0r * d1i + o0i * d1r; // flip bit11
            const float dp2r = d0r * o1r - d0i * o1i, dp2i = d0r * o1i + d0i * o1r; // flip bit10
            const float dp3r = o0r * o1r - o0i * o1i, dp3i = o0r * o1i + o0i * o1r; // flip both
            #pragma unroll
            for (int k = 0; k < 8; ++k) {
                const unsigned a0 = wbyte ^ ((unsigned)(2 * k) << 3);
                const unsigned a1 = a0 ^ 8u;
                const float2 o_0 = *(const float2*)((const char*)rb + a0);
                const float2 o_1 = *(const float2*)((const char*)rb + a1);
                const float2 u_0 = *(const float2*)((const char*)rb + (a0 ^ 0x4040u));
                const float2 u_1 = *(const float2*)((const char*)rb + (a1 ^ 0x4040u));
                const float2 v_0 = *(const float2*)((const char*)rb + (a0 ^ 0x2020u));
                const float2 v_1 = *(const float2*)((const char*)rb + (a1 ^ 0x2020u));
                const float2 w_0 = *(const float2*)((const char*)rb + (a0 ^ 0x6060u));
                const float2 w_1 = *(const float2*)((const char*)rb + (a1 ^ 0x6060u));
                const f32x2 orr = f32x2{o_0.x, o_1.x}, oii = f32x2{o_0.y, o_1.y};
                const f32x2 p1r = f32x2{u_0.x, u_1.x}, p1i = f32x2{u_0.y, u_1.y};
                const f32x2 p2r = f32x2{v_0.x, v_1.x}, p2i = f32x2{v_0.y, v_1.y};
                const f32x2 p3r = f32x2{w_0.x, w_1.x}, p3i = f32x2{w_0.y, w_1.y};
                rp[k] = dwr*orr - dwi*oii + dp1r*p1r - dp1i*p1i + dp2r*p2r - dp2i*p2i + dp3r*p3r - dp3i*p3i;
                ip[k] = dwi*orr + dwr*oii + dp1i*p1r + dp1r*p1i + dp2i*p2r + dp2r*p2i + dp3i*p3r + dp3r*p3i;
            }
        }

        // ==== wire 2 (state bit 9 = lane bit 5): shfl_xor 32 ====
        {
            const float4 ga = *(const float4*)(&gm[l * NQ + 2][0]);
            const float4 gb_ = *(const float4*)(&gm[l * NQ + 2][4]);
            const int lb = (lane >> 5) & 1;
            const float cMer = lb ? gb_.z : ga.x, cMei = lb ? gb_.w : ga.y;
            const float cOtr = lb ? gb_.x : ga.z, cOti = lb ? gb_.y : ga.w;
            #pragma unroll
            for (int k = 0; k < 8; ++k) {
                const f32x2 pR = shfl2(rp[k], 32), pI = shfl2(ip[k], 32);
                const f32x2 nr = cMer*rp[k] - cMei*ip[k] + cOtr*pR - cOti*pI;
                const f32x2 ni = cMei*rp[k] + cMer*ip[k] + cOti*pR + cOtr*pI;
                rp[k] = nr; ip[k] = ni;
            }
        }
        // ==== wire 3 (lane bit 4): ds_swizzle xor16 ====
        {
            const float4 ga = *(const float4*)(&gm[l * NQ + 3][0]);
            const float4 gb_ = *(const float4*)(&gm[l * NQ + 3][4]);
            const int lb = (lane >> 4) & 1;
            const float cMer = lb ? gb_.z : ga.x, cMei = lb ? gb_.w : ga.y;
            const float cOtr = lb ? gb_.x : ga.z, cOti = lb ? gb_.y : ga.w;
            #pragma unroll
            for (int k = 0; k < 8; ++k) {
                const f32x2 pR = swz2<0x401F>(rp[k]), pI = swz2<0x401F>(ip[k]);
                const f32x2 nr = cMer*rp[k] - cMei*ip[k] + cOtr*pR - cOti*pI;
                const f32x2 ni = cMei*rp[k] + cMer*ip[k] + cOti*pR + cOtr*pI;
                rp[k] = nr; ip[k] = ni;
            }
        }
        // ==== wire 4 (lane bit 3): ds_swizzle xor8 ====
        {
            const float4 ga = *(const float4*)(&gm[l * NQ + 4][0]);
            const float4 gb_ = *(const float4*)(&gm[l * NQ + 4][4]);
            const int lb = (lane >> 3) & 1;
            const float cMer = lb ? gb_.z : ga.x, cMei = lb ? gb_.w : ga.y;
            const float cOtr = lb ? gb_.x : ga.z, cOti = lb ? gb_.y : ga.w;
            #pragma unroll
            for (int k = 0; k < 8; ++k) {
                const f32x2 pR = swz2<0x201F>(rp[k]), pI = swz2<0x201F>(ip[k]);
                const f32x2 nr = cMer*rp[k] - cMei*ip[k] + cOtr*pR - cOti*pI;
                const f32x2 ni = cMei*rp[k] + cMer*ip[k] + cOti*pR + cOtr*pI;
                rp[k] = nr; ip[k] = ni;
            }
        }
        // ==== wire 5 (lane bit 2): ds_swizzle xor4 ====
        {
            const float4 ga = *(const float4*)(&gm[l * NQ + 5][0]);
            const float4 gb_ = *(const float4*)(&gm[l * NQ + 5][4]);
            const int lb = (lane >> 2) & 1;
            const float cMer = lb ? gb_.z : ga.x, cMei = lb ? gb_.w : ga.y;
            const float cOtr = lb ? gb_.x : ga.z, cOti = lb ? gb_.y : ga.w;
            #pragma unroll
            for (int k = 0; k < 8; ++k) {
                const f32x2 pR = swz2<0x101F>(rp[k]), pI = swz2<0x101F>(ip[k]);
                const f32x2 nr = cMer*rp[k] - cMei*ip[k] + cOtr*pR - cOti*pI;
                const f32x2 ni = cMei*rp[k] + cMer*ip[k] + cOti*pR + cOtr*pI;
                rp[k] = nr; ip[k] = ni;
            }
        }
        // ==== wire 6 (lane bit 1): DPP quad_perm xor2 ====
        {
            const float4 ga = *(const float4*)(&gm[l * NQ + 6][0]);
            const float4 gb_ = *(const float4*)(&gm[l * NQ + 6][4]);
            const int lb = (lane >> 1) & 1;
            const float cMer = lb ? gb_.z : ga.x, cMei = lb ? gb_.w : ga.y;
            const float cOtr = lb ? gb_.x : ga.z, cOti = lb ? gb_.y : ga.w;
            #pragma unroll
            for (int k = 0; k < 8; ++k) {
                const f32x2 pR = dpp2<0x4E>(rp[k]), pI = dpp2<0x4E>(ip[k]);
                const f32x2 nr = cMer*rp[k] - cMei*ip[k] + cOtr*pR - cOti*pI;
                const f32x2 ni = cMei*rp[k] + cMer*ip[k] + cOti*pR + cOtr*pI;
                rp[k] = nr; ip[k] = ni;
            }
        }
        // ==== wire 7 (lane bit 0): DPP quad_perm xor1 ====
        {
            const float4 ga = *(const float4*)(&gm[l * NQ + 7][0]);
            const float4 gb_ = *(const float4*)(&gm[l * NQ + 7][4]);
            const int lb = lane & 1;
            const float cMer = lb ? gb_.z : ga.x, cMei = lb ? gb_.w : ga.y;
            const float cOtr = lb ? gb_.x : ga.z, cOti = lb ? gb_.y : ga.w;
            #pragma unroll
            for (int k = 0; k < 8; ++k) {
                const f32x2 pR = dpp2<0xB1>(rp[k]), pI = dpp2<0xB1>(ip[k]);
                const f32x2 nr = cMer*rp[k] - cMei*ip[k] + cOtr*pR - cOti*pI;
                const f32x2 ni = cMei*rp[k] + cMer*ip[k] + cOti*pR + cOtr*pI;
                rp[k] = nr; ip[k] = ni;
            }
        }
        // ==== wires 8,9,10 (reg-index bits 2,1,0) ====
        #pragma unroll
        for (int wq = 8; wq <= 10; ++wq) {
            const int rb2 = 10 - wq;
            const float4 ga = *(const float4*)(&gm[l * NQ + wq][0]);
            const float4 gb_ = *(const float4*)(&gm[l * NQ + wq][4]);
            #pragma unroll
            for (int h = 0; h < 4; ++h) {
                const int k0 = ((h >> rb2) << (rb2 + 1)) | (h & ((1 << rb2) - 1));
                const int k1 = k0 | (1 << rb2);
                const f32x2 a0r = rp[k0], a0i = ip[k0], a1r = rp[k1], a1i = ip[k1];
                rp[k0] = ga.x*a0r - ga.y*a0i + ga.z*a1r - ga.w*a1i;
                ip[k0] = ga.y*a0r + ga.x*a0i + ga.w*a1r + ga.z*a1i;
                rp[k1] = gb_.x*a0r - gb_.y*a0i + gb_.z*a1r - gb_.w*a1i;
                ip[k1] = gb_.y*a0r + gb_.x*a0i + gb_.w*a1r + gb_.z*a1i;
            }
        }
        // ==== wire 11 (intra f32x2) ====
        {
            const float4 ga = *(const float4*)(&gm[l * NQ + 11][0]);
            const float4 gb_ = *(const float4*)(&gm[l * NQ + 11][4]);
            #pragma unroll
            for (int k = 0; k < 8; ++k) {
                const float a0r = rp[k].x, a0i = ip[k].x, a1r = rp[k].y, a1i = ip[k].y;
                rp[k].x = ga.x*a0r - ga.y*a0i + ga.z*a1r - ga.w*a1i;
                ip[k].x = ga.y*a0r + ga.x*a0i + ga.w*a1r + ga.z*a1i;
                rp[k].y = gb_.x*a0r - gb_.y*a0i + gb_.z*a1r - gb_.w*a1i;
                ip[k].y = gb_.y*a0r + gb_.x*a0i + gb_.w*a1r + gb_.z*a1i;
            }
        }

        // ==== scatter-write through inverse ring map ====
        {
            unsigned sbase = 0;
            #pragma unroll
            for (int j = 0; j < 6; ++j) if ((lane >> j) & 1) sbase ^= TB.lcol[l][j];
            if (b10) sbase ^= TB.lcol[l][6];
            if (b11) sbase ^= TB.lcol[l][7];
            #pragma unroll
            for (int k = 0; k < 8; ++k) {
                *(float2*)((char*)wb + (sbase ^ TB.scol[l][2 * k]))     = make_float2(rp[k].x, ip[k].x);
                *(float2*)((char*)wb + (sbase ^ TB.scol[l][2 * k + 1])) = make_float2(rp[k].y, ip[k].y);
            }
        }
        __syncthreads();
    }

    // ---- fused <Z_q> + linear head (plain layout in stbuf[0]) ----
    {
        float CS[16];
        CS[0] = hw[11]; CS[1] = -hw[11];
        #pragma unroll
        for (int bit = 1; bit < 4; ++bit) {
            const float h = hw[11 - bit];
            #pragma unroll
            for (int j = (1 << bit) - 1; j >= 0; --j) {
                CS[j | (1 << bit)] = CS[j] - h;
                CS[j]              = CS[j] + h;
            }
        }
        float CW = b11 ? -hw[0] : hw[0];
        CW += b10 ? -hw[1] : hw[1];
        #pragma unroll
        for (int q = 2; q <= 7; ++q)
            CW += ((lane >> (7 - q)) & 1) ? -hw[q] : hw[q];

        f32x2 acc = f32x2{0.f, 0.f};
        #pragma unroll
        for (int k = 0; k < 8; ++k) {
            const unsigned a0 = wbyte ^ ((unsigned)(2 * k) << 3);
            const float2 v0 = *(const float2*)((const char*)stbuf[0] + a0);
            const float2 v1 = *(const float2*)((const char*)stbuf[0] + (a0 ^ 8u));
            const f32x2 vr = f32x2{v0.x, v1.x}, vi = f32x2{v0.y, v1.y};
            const f32x2 pr = vr * vr + vi * vi;
            acc += pr * f32x2{CW + CS[2 * k], CW + CS[2 * k + 1]};
        }
        float sres = acc.x + acc.y;
        #pragma unroll
        for (int off = 32; off >= 1; off >>= 1)
            sres += __shfl_xor(sres, off, 64);
        if ((tid & 63) == 0) wred[wv] = sres;
        __syncthreads();
        if (tid == 0) out[b] = wred[0] + wred[1] + wred[2] + wred[3] + hb[0];
    }
}

extern "C" void kernel_launch(void* const* d_in, const int* in_sizes, int n_in,
                              void* d_out, int out_size, void* d_ws, size_t ws_size,
                              hipStream_t stream) {
    const float* x  = (const float*)d_in[0];
    const float* wt = (const float*)d_in[1];
    const float* hw = (const float*)d_in[2];
    const float* hb = (const float*)d_in[3];
    float* outp = (float*)d_out;
    const int B = in_sizes[0] / NQ;      // 512
    qsim_kernel<<<B, NT, 0, stream>>>(x, wt, hw, hb, outp);
}

// Round 6
// 32.545 us; speedup vs baseline: 3.4184x; 1.0757x over previous
//
#include <hip/hip_runtime.h>

#define NQ 12
#define NL 4
#define NT 256
// state bits: 11,10 = wave id (4 waves), 9..4 = lane bits 5..0, 3..0 = slot
// per lane: 16 amps in 8 f32x2 pairs (slot bit0 = f32x2 component)

typedef float f32x2 __attribute__((ext_vector_type(2)));

constexpr unsigned sidx_c(unsigned x) { return x ^ ((x >> 4) & 15u) ^ ((x >> 8) & 15u); }

constexpr unsigned gmap_inv(int l, unsigned v) {
    // inverse of the layer-l fused CNOT-ring map
    int r = l + 1; unsigned x = v;
    for (int q = 0; q < NQ; ++q) {
        int cb = NQ - 1 - q, tw = (q + r) % NQ, tb = NQ - 1 - tw;
        x ^= ((x >> cb) & 1u) << tb;
    }
    return x;
}

struct Tabs {
    unsigned lcol[3][8];    // scatter byte-cols (layers 0..2): [0..5]=bits 4..9, [6]=bit10, [7]=bit11
    unsigned scol[3][16];   // scatter byte-offset per slot nibble
    unsigned rfin[NQ];      // measurement parity masks: sign_q(x) = parity(x & rfin[q])
};
constexpr Tabs make_tabs() {
    Tabs T{};
    for (int l = 0; l < 3; ++l) {
        unsigned colb[12];
        for (int bit = 0; bit < 12; ++bit) colb[bit] = sidx_c(gmap_inv(l, 1u << bit)) << 3;
        for (int j = 0; j < 6; ++j) T.lcol[l][j] = colb[4 + j];
        T.lcol[l][6] = colb[10];
        T.lcol[l][7] = colb[11];
        for (int s = 0; s < 16; ++s) {
            unsigned v = 0;
            for (int bp = 0; bp < 4; ++bp) if ((s >> bp) & 1) v ^= colb[bp];
            T.scol[l][s] = v;
        }
    }
    for (int q = 0; q < NQ; ++q) {
        const int bpos = 11 - q;              // wire q <-> final index bit 11-q
        unsigned m = 0;
        for (int j = 0; j < 12; ++j)
            m |= ((gmap_inv(3, 1u << j) >> bpos) & 1u) << j;
        T.rfin[q] = m;
    }
    return T;
}
__constant__ Tabs TB = make_tabs();
constexpr Tabs CT = make_tabs();

template<int CTRL>
__device__ __forceinline__ f32x2 dpp2(f32x2 v) {
    f32x2 r;
    r.x = __int_as_float(__builtin_amdgcn_update_dpp(__float_as_int(v.x), __float_as_int(v.x), CTRL, 0xF, 0xF, false));
    r.y = __int_as_float(__builtin_amdgcn_update_dpp(__float_as_int(v.y), __float_as_int(v.y), CTRL, 0xF, 0xF, false));
    return r;
}
__device__ __forceinline__ void pswap32(f32x2 v, f32x2& lo, f32x2& hi) {
    float ax = v.x, bx = v.x;
    asm("v_permlane32_swap_b32 %0, %1" : "+v"(ax), "+v"(bx));
    float ay = v.y, by = v.y;
    asm("v_permlane32_swap_b32 %0, %1" : "+v"(ay), "+v"(by));
    lo = f32x2{ax, ay}; hi = f32x2{bx, by};
}
__device__ __forceinline__ void pswap16(f32x2 v, f32x2& ev, f32x2& od) {
    float ax = v.x, bx = v.x;
    asm("v_permlane16_swap_b32 %0, %1" : "+v"(ax), "+v"(bx));
    float ay = v.y, by = v.y;
    asm("v_permlane16_swap_b32 %0, %1" : "+v"(ay), "+v"(by));
    ev = f32x2{ax, ay}; od = f32x2{bx, by};
}

// wires 2..11 of one layer, all in registers / VALU cross-lane
__device__ __forceinline__ void gates2to11(f32x2 rp[8], f32x2 ip[8], const float (*gmL)[8], int lane) {
    // wire 2 (lane bit5, xor32): permlane32_swap, r0/r1 coefficient form
    {
        const float4 ga = *(const float4*)&gmL[2][0];
        const float4 gb = *(const float4*)&gmL[2][4];
        const int h = (lane >> 5) & 1;
        const float car = h ? gb.x : ga.x, cai = h ? gb.y : ga.y;
        const float cbr = h ? gb.z : ga.z, cbi = h ? gb.w : ga.w;
        #pragma unroll
        for (int k = 0; k < 8; ++k) {
            f32x2 r0r, r1r, r0i, r1i;
            pswap32(rp[k], r0r, r1r);
            pswap32(ip[k], r0i, r1i);
            rp[k] = car*r0r - cai*r0i + cbr*r1r - cbi*r1i;
            ip[k] = cai*r0r + car*r0i + cbi*r1r + cbr*r1i;
        }
    }
    // wire 3 (lane bit4, xor16): permlane16_swap
    {
        const float4 ga = *(const float4*)&gmL[3][0];
        const float4 gb = *(const float4*)&gmL[3][4];
        const int h = (lane >> 4) & 1;
        const float car = h ? gb.x : ga.x, cai = h ? gb.y : ga.y;
        const float cbr = h ? gb.z : ga.z, cbi = h ? gb.w : ga.w;
        #pragma unroll
        for (int k = 0; k < 8; ++k) {
            f32x2 r0r, r1r, r0i, r1i;
            pswap16(rp[k], r0r, r1r);
            pswap16(ip[k], r0i, r1i);
            rp[k] = car*r0r - cai*r0i + cbr*r1r - cbi*r1i;
            ip[k] = cai*r0r + car*r0i + cbi*r1r + cbr*r1i;
        }
    }
    // wire 4 (lane bit3, xor8): DPP row_ror:8 partner
    {
        const float4 ga = *(const float4*)&gmL[4][0];
        const float4 gb = *(const float4*)&gmL[4][4];
        const int h = (lane >> 3) & 1;
        const float cMer = h ? gb.z : ga.x, cMei = h ? gb.w : ga.y;
        const float cOtr = h ? gb.x : ga.z, cOti = h ? gb.y : ga.w;
        #pragma unroll
        for (int k = 0; k < 8; ++k) {
            const f32x2 pR = dpp2<0x128>(rp[k]), pI = dpp2<0x128>(ip[k]);
            const f32x2 nr = cMer*rp[k] - cMei*ip[k] + cOtr*pR - cOti*pI;
            const f32x2 ni = cMei*rp[k] + cMer*ip[k] + cOti*pR + cOtr*pI;
            rp[k] = nr; ip[k] = ni;
        }
    }
    // wire 5 (lane bit2, xor4): DPP chain half_mirror(^7) . quad(^2) . quad(^1)
    {
        const float4 ga = *(const float4*)&gmL[5][0];
        const float4 gb = *(const float4*)&gmL[5][4];
        const int h = (lane >> 2) & 1;
        const float cMer = h ? gb.z : ga.x, cMei = h ? gb.w : ga.y;
        const float cOtr = h ? gb.x : ga.z, cOti = h ? gb.y : ga.w;
        #pragma unroll
        for (int k = 0; k < 8; ++k) {
            const f32x2 pR = dpp2<0xB1>(dpp2<0x4E>(dpp2<0x141>(rp[k])));
            const f32x2 pI = dpp2<0xB1>(dpp2<0x4E>(dpp2<0x141>(ip[k])));
            const f32x2 nr = cMer*rp[k] - cMei*ip[k] + cOtr*pR - cOti*pI;
            const f32x2 ni = cMei*rp[k] + cMer*ip[k] + cOti*pR + cOtr*pI;
            rp[k] = nr; ip[k] = ni;
        }
    }
    // wire 6 (lane bit1, xor2): quad_perm
    {
        const float4 ga = *(const float4*)&gmL[6][0];
        const float4 gb = *(const float4*)&gmL[6][4];
        const int h = (lane >> 1) & 1;
        const float cMer = h ? gb.z : ga.x, cMei = h ? gb.w : ga.y;
        const float cOtr = h ? gb.x : ga.z, cOti = h ? gb.y : ga.w;
        #pragma unroll
        for (int k = 0; k < 8; ++k) {
            const f32x2 pR = dpp2<0x4E>(rp[k]), pI = dpp2<0x4E>(ip[k]);
            const f32x2 nr = cMer*rp[k] - cMei*ip[k] + cOtr*pR - cOti*pI;
            const f32x2 ni = cMei*rp[k] + cMer*ip[k] + cOti*pR + cOtr*pI;
            rp[k] = nr; ip[k] = ni;
        }
    }
    // wire 7 (lane bit0, xor1): quad_perm
    {
        const float4 ga = *(const float4*)&gmL[7][0];
        const float4 gb = *(const float4*)&gmL[7][4];
        const int h = lane & 1;
        const float cMer = h ? gb.z : ga.x, cMei = h ? gb.w : ga.y;
        const float cOtr = h ? gb.x : ga.z, cOti = h ? gb.y : ga.w;
        #pragma unroll
        for (int k = 0; k < 8; ++k) {
            const f32x2 pR = dpp2<0xB1>(rp[k]), pI = dpp2<0xB1>(ip[k]);
            const f32x2 nr = cMer*rp[k] - cMei*ip[k] + cOtr*pR - cOti*pI;
            const f32x2 ni = cMei*rp[k] + cMer*ip[k] + cOti*pR + cOtr*pI;
            rp[k] = nr; ip[k] = ni;
        }
    }
    // wires 8..10 (reg-index bits 2..0)
    #pragma unroll
    for (int wq = 8; wq <= 10; ++wq) {
        const int rb2 = 10 - wq;
        const float4 ga = *(const float4*)&gmL[wq][0];
        const float4 gb = *(const float4*)&gmL[wq][4];
        #pragma unroll
        for (int h2 = 0; h2 < 4; ++h2) {
            const int k0 = ((h2 >> rb2) << (rb2 + 1)) | (h2 & ((1 << rb2) - 1));
            const int k1 = k0 | (1 << rb2);
            const f32x2 a0r = rp[k0], a0i = ip[k0], a1r = rp[k1], a1i = ip[k1];
            rp[k0] = ga.x*a0r - ga.y*a0i + ga.z*a1r - ga.w*a1i;
            ip[k0] = ga.y*a0r + ga.x*a0i + ga.w*a1r + ga.z*a1i;
            rp[k1] = gb.x*a0r - gb.y*a0i + gb.z*a1r - gb.w*a1i;
            ip[k1] = gb.y*a0r + gb.x*a0i + gb.w*a1r + gb.z*a1i;
        }
    }
    // wire 11 (intra f32x2), pk-ized via coefficient pairs
    {
        const float4 ga = *(const float4*)&gmL[11][0];
        const float4 gb = *(const float4*)&gmL[11][4];
        const f32x2 K0r = f32x2{ga.x, gb.x}, K0i = f32x2{ga.y, gb.y};
        const f32x2 K1r = f32x2{ga.z, gb.z}, K1i = f32x2{ga.w, gb.w};
        #pragma unroll
        for (int k = 0; k < 8; ++k) {
            const float a0r = rp[k].x, a0i = ip[k].x, a1r = rp[k].y, a1i = ip[k].y;
            rp[k] = K0r*a0r - K0i*a0i + K1r*a1r - K1i*a1i;
            ip[k] = K0i*a0r + K0r*a0i + K1i*a1r + K1r*a1i;
        }
    }
}

// read state from LDS fused with wires 0,1 (wave bits 11,10) as a 4-term butterfly
__device__ __forceinline__ void read_w01(f32x2 rp[8], f32x2 ip[8], const float2* st, unsigned wbyte,
                                         const float (*gmL)[8], int b11, int b10) {
    const float4 ga0 = *(const float4*)&gmL[0][0];
    const float4 gb0 = *(const float4*)&gmL[0][4];
    const float4 ga1 = *(const float4*)&gmL[1][0];
    const float4 gb1 = *(const float4*)&gmL[1][4];
    const float d0r = b11 ? gb0.z : ga0.x, d0i = b11 ? gb0.w : ga0.y;
    const float o0r = b11 ? gb0.x : ga0.z, o0i = b11 ? gb0.y : ga0.w;
    const float d1r = b10 ? gb1.z : ga1.x, d1i = b10 ? gb1.w : ga1.y;
    const float o1r = b10 ? gb1.x : ga1.z, o1i = b10 ? gb1.y : ga1.w;
    const float dwr  = d0r*d1r - d0i*d1i, dwi  = d0r*d1i + d0i*d1r;   // own
    const float dp1r = o0r*d1r - o0i*d1i, dp1i = o0r*d1i + o0i*d1r;   // flip bit11
    const float dp2r = d0r*o1r - d0i*o1i, dp2i = d0r*o1i + d0i*o1r;   // flip bit10
    const float dp3r = o0r*o1r - o0i*o1i, dp3i = o0r*o1i + o0i*o1r;   // flip both
    #pragma unroll
    for (int k = 0; k < 8; ++k) {
        const unsigned a0 = wbyte ^ ((unsigned)(2 * k) << 3);
        const unsigned a1 = a0 ^ 8u;
        const float2 o_0 = *(const float2*)((const char*)st + a0);
        const float2 o_1 = *(const float2*)((const char*)st + a1);
        const float2 v_0 = *(const float2*)((const char*)st + (a0 ^ 0x2020u));
        const float2 v_1 = *(const float2*)((const char*)st + (a1 ^ 0x2020u));
        const float2 u_0 = *(const float2*)((const char*)st + (a0 ^ 0x4040u));
        const float2 u_1 = *(const float2*)((const char*)st + (a1 ^ 0x4040u));
        const float2 w_0 = *(const float2*)((const char*)st + (a0 ^ 0x6060u));
        const float2 w_1 = *(const float2*)((const char*)st + (a1 ^ 0x6060u));
        const f32x2 orr = f32x2{o_0.x, o_1.x}, oii = f32x2{o_0.y, o_1.y};
        const f32x2 p2r = f32x2{v_0.x, v_1.x}, p2i = f32x2{v_0.y, v_1.y};
        const f32x2 p1r = f32x2{u_0.x, u_1.x}, p1i = f32x2{u_0.y, u_1.y};
        const f32x2 p3r = f32x2{w_0.x, w_1.x}, p3i = f32x2{w_0.y, w_1.y};
        rp[k] = dwr*orr - dwi*oii + dp1r*p1r - dp1i*p1i + dp2r*p2r - dp2i*p2i + dp3r*p3r - dp3i*p3i;
        ip[k] = dwi*orr + dwr*oii + dp1i*p1r + dp1r*p1i + dp2i*p2r + dp2r*p2i + dp3i*p3r + dp3r*p3i;
    }
}

__device__ __forceinline__ void scatter_l(const f32x2 rp[8], const f32x2 ip[8], float2* st,
                                          int l, int lane, int b10, int b11) {
    unsigned sbase = 0;
    #pragma unroll
    for (int j = 0; j < 6; ++j) if ((lane >> j) & 1) sbase ^= TB.lcol[l][j];
    if (b10) sbase ^= TB.lcol[l][6];
    if (b11) sbase ^= TB.lcol[l][7];
    #pragma unroll
    for (int k = 0; k < 8; ++k) {
        *(float2*)((char*)st + (sbase ^ TB.scol[l][2 * k]))     = make_float2(rp[k].x, ip[k].x);
        *(float2*)((char*)st + (sbase ^ TB.scol[l][2 * k + 1])) = make_float2(rp[k].y, ip[k].y);
    }
}

__global__ __launch_bounds__(NT) void qsim_kernel(
    const float* __restrict__ xin,   // (B,12)
    const float* __restrict__ wts,   // (4,12,3)
    const float* __restrict__ hw,    // (12,)
    const float* __restrict__ hb,    // (1,)
    float* __restrict__ out)         // (B,)
{
    __shared__ float2 st[4096];          // 32 KB single buffer
    __shared__ float  gm[NL * NQ][8];
    __shared__ float  wred[4];

    const int tid  = threadIdx.x;
    const int lane = tid & 63;
    const int wv   = tid >> 6;
    const int b    = blockIdx.x;
    const int b11  = wv >> 1, b10 = wv & 1;

    // Rot matrices (threads 0..47) — keep precise trig here
    if (tid < NL * NQ) {
        const float phi = wts[tid * 3 + 0];
        const float th  = wts[tid * 3 + 1];
        const float om  = wts[tid * 3 + 2];
        const float ct  = cosf(0.5f * th), stt = sinf(0.5f * th);
        const float apo = -0.5f * (phi + om), amo = -0.5f * (phi - om);
        const float epr = cosf(apo), epi = sinf(apo);
        const float emr = cosf(amo), emi = sinf(amo);
        float* g = gm[tid];
        g[0] =  epr * ct;  g[1] =  epi * ct;   // u00
        g[2] = -emr * stt; g[3] =  emi * stt;  // u01
        g[4] =  emr * stt; g[5] =  emi * stt;  // u10
        g[6] =  epr * ct;  g[7] = -epi * ct;   // u11
    }

    // embedding angles (bit bp <-> wire 11-bp), fast trig (args ~N(0,1)/2)
    float cv[NQ], sv[NQ];
    #pragma unroll
    for (int bp = 0; bp < NQ; ++bp) {
        const float a = 0.5f * xin[b * NQ + (NQ - 1 - bp)];
        cv[bp] = __cosf(a); sv[bp] = __sinf(a);
    }
    // slot magnitudes
    float MS[16];
    MS[0] = cv[0]; MS[1] = sv[0];
    #pragma unroll
    for (int bit = 1; bit < 4; ++bit) {
        #pragma unroll
        for (int j = (1 << bit) - 1; j >= 0; --j) {
            MS[j | (1 << bit)] = MS[j] * sv[bit];
            MS[j]              = MS[j] * cv[bit];
        }
    }

    const unsigned xbase = ((unsigned)wv << 10) | ((unsigned)lane << 4);
    const unsigned wbyte = (xbase ^ ((xbase >> 4) & 15u) ^ ((xbase >> 8) & 15u)) << 3;

    __syncthreads();   // gm ready

    f32x2 rp[8], ip[8];

    // ---- layer 0 fully in registers: wires 0,1 collapse to one 2-qubit matvec ----
    {
        const float m00 = cv[11]*cv[10], m01 = cv[11]*sv[10];
        const float m10 = sv[11]*cv[10], m11s = sv[11]*sv[10];
        const float* G0 = gm[0];
        const float* G1 = gm[1];
        const float u0ar = b11 ? G0[4] : G0[0], u0ai = b11 ? G0[5] : G0[1];  // U0[b11][0]
        const float u0br = b11 ? G0[6] : G0[2], u0bi = b11 ? G0[7] : G0[3];  // U0[b11][1]
        const float u1ar = b10 ? G1[4] : G1[0], u1ai = b10 ? G1[5] : G1[1];
        const float u1br = b10 ? G1[6] : G1[2], u1bi = b10 ? G1[7] : G1[3];
        // v00=(m00,0) v01=(0,-m01) v10=(0,-m10) v11=(-m11s,0)  [(-i)^popc phases]
        const float t0r = u0ar*m00 + u0bi*m10;
        const float t0i = u0ai*m00 - u0br*m10;
        const float t1r = u0ai*m01 - u0br*m11s;
        const float t1i = -(u0ar*m01) - u0bi*m11s;
        float Ar = u1ar*t0r - u1ai*t0i + u1br*t1r - u1bi*t1i;
        float Ai = u1ai*t0r + u1ar*t0i + u1bi*t1r + u1br*t1i;
        // lane magnitude + (-i)^popc(lane)
        float mm = 1.f;
        #pragma unroll
        for (int j = 0; j < 6; ++j) mm *= ((lane >> j) & 1) ? sv[4 + j] : cv[4 + j];
        Ar *= mm; Ai *= mm;
        const int pcl = __popc((unsigned)lane) & 3;
        float Br, Bi;
        if      (pcl == 0) { Br =  Ar; Bi =  Ai; }
        else if (pcl == 1) { Br =  Ai; Bi = -Ar; }
        else if (pcl == 2) { Br = -Ar; Bi = -Ai; }
        else               { Br = -Ai; Bi =  Ar; }
        #pragma unroll
        for (int s = 0; s < 16; ++s) {
            const float m = MS[s];
            const int pc = __builtin_popcount((unsigned)s) & 3;
            float ar, ai;
            if      (pc == 0) { ar =  Br*m; ai =  Bi*m; }
            else if (pc == 1) { ar =  Bi*m; ai = -Br*m; }
            else if (pc == 2) { ar = -Br*m; ai = -Bi*m; }
            else              { ar = -Bi*m; ai =  Br*m; }
            if (s & 1) { rp[s >> 1].y = ar; ip[s >> 1].y = ai; }
            else       { rp[s >> 1].x = ar; ip[s >> 1].x = ai; }
        }
        gates2to11(rp, ip, &gm[0], lane);
        scatter_l(rp, ip, st, 0, lane, b10, b11);
    }
    __syncthreads();

    // ---- layers 1..3 ----
    for (int l = 1; l < NL; ++l) {
        read_w01(rp, ip, st, wbyte, &gm[l * NQ], b11, b10);
        gates2to11(rp, ip, &gm[l * NQ], lane);
        if (l < 3) {
            __syncthreads();               // all reads done before overwrite
            scatter_l(rp, ip, st, l, lane, b10, b11);
            __syncthreads();
        }
    }

    // ---- fused layer-3 ring + <Z_q> + linear head, all in registers ----
    {
        float CS[16];
        #pragma unroll
        for (int s = 0; s < 16; ++s) CS[s] = 0.f;
        #pragma unroll
        for (int q = 0; q < NQ; ++q) {
            const unsigned m = CT.rfin[q];
            const float wq = (__popc(xbase & m) & 1) ? -hw[q] : hw[q];
            #pragma unroll
            for (int s = 0; s < 16; ++s)
                CS[s] += (__builtin_popcount((unsigned)s & m) & 1) ? -wq : wq;
        }
        f32x2 acc = f32x2{0.f, 0.f};
        #pragma unroll
        for (int k = 0; k < 8; ++k) {
            const f32x2 pr = rp[k]*rp[k] + ip[k]*ip[k];
            acc += pr * f32x2{CS[2 * k], CS[2 * k + 1]};
        }
        float sres = acc.x + acc.y;
        #pragma unroll
        for (int off = 32; off >= 1; off >>= 1)
            sres += __shfl_xor(sres, off, 64);
        if ((tid & 63) == 0) wred[wv] = sres;
        __syncthreads();
        if (tid == 0) out[b] = wred[0] + wred[1] + wred[2] + wred[3] + hb[0];
    }
}

extern "C" void kernel_launch(void* const* d_in, const int* in_sizes, int n_in,
                              void* d_out, int out_size, void* d_ws, size_t ws_size,
                              hipStream_t stream) {
    const float* x  = (const float*)d_in[0];
    const float* wt = (const float*)d_in[1];
    const float* hw = (const float*)d_in[2];
    const float* hb = (const float*)d_in[3];
    float* outp = (float*)d_out;
    const int B = in_sizes[0] / NQ;      // 512
    qsim_kernel<<<B, NT, 0, stream>>>(x, wt, hw, hb, outp);
}